// Round 1
// baseline (3518.196 us; speedup 1.0000x reference)
//
#include <hip/hip_runtime.h>
#include <stdint.h>

// Problem constants (fixed by setup_inputs)
#define Bn 256
#define Hn 768
#define Tn 128
#define KSTEPS 24    // Hn / 32 (K per mfma)
#define JTILES 48    // Hn / 16

typedef __attribute__((ext_vector_type(8))) short short8;   // 8 bf16 = 4 VGPRs
typedef __attribute__((ext_vector_type(4))) float floatx4;  // mfma C/D

static __device__ __forceinline__ unsigned short f2bf(float f) {
  // round-to-nearest-even bf16 (values are finite; no NaN path needed)
  unsigned int x = __float_as_uint(f);
  x += 0x7fffu + ((x >> 16) & 1u);
  return (unsigned short)(x >> 16);
}
static __device__ __forceinline__ float bf2f(unsigned short u) {
  return __uint_as_float(((unsigned int)u) << 16);
}

// ---------------------------------------------------------------------------
// Swizzle W_hh (2304x768 fp32, row-major) into B-fragment-ordered bf16 hi/lo
// planes. Chunk = (row-tile n0/16, kstep k0/32): 64 lanes x 8 bf16 = 1 KiB,
// lane L holds W[n0+(L&15)][k0+(L>>4)*8 .. +8]. B-frag load is then a fully
// coalesced global_load_dwordx4 at chunk_base + lane*16B.
// ---------------------------------------------------------------------------
__global__ void swz_w(const float* __restrict__ W,
                      unsigned short* __restrict__ whi,
                      unsigned short* __restrict__ wlo) {
  int i = blockIdx.x * blockDim.x + threadIdx.x;  // one thread per 8 k's
  if (i >= 2304 * (Hn / 8)) return;
  int n  = i / (Hn / 8);
  int k0 = (i % (Hn / 8)) * 8;
  int tile = n >> 4, kstep = k0 >> 5;
  int lane = (n & 15) + (((k0 >> 3) & 3) << 4);
  size_t off = ((size_t)(tile * KSTEPS + kstep)) * 512 + (size_t)lane * 8;
  const float* src = W + (size_t)n * Hn + k0;
  short8 h8, l8;
#pragma unroll
  for (int q = 0; q < 8; ++q) {
    float w = src[q];
    unsigned short hb = f2bf(w);
    h8[q] = (short)hb;
    l8[q] = (short)f2bf(w - bf2f(hb));
  }
  *(short8*)(whi + off) = h8;
  *(short8*)(wlo + off) = l8;
}

// ---------------------------------------------------------------------------
// Init: h0 = context (fp32 plane + bf16 hi/lo planes), zero delta accumulator.
// ---------------------------------------------------------------------------
__global__ void init_h(const float* __restrict__ ctx, float* __restrict__ hf,
                       unsigned short* __restrict__ hhi,
                       unsigned short* __restrict__ hlo,
                       float* __restrict__ ddot) {
  int i = blockIdx.x * blockDim.x + threadIdx.x;
  if (i < Bn * Hn) {
    float c = ctx[i];
    hf[i] = c;
    unsigned short hb = f2bf(c);
    hhi[i] = hb;
    hlo[i] = f2bf(c - bf2f(hb));
  }
  if (i < Tn * Bn) ddot[i] = 0.f;
}

// ---------------------------------------------------------------------------
// One GRU step. Block = 1 wave (64 thr). Wave computes 2 m-tiles (16 rows
// each) x 16 hidden units x 3 gates via mfma_f32_16x16x32_bf16, split-bf16
// (A_hi*B_hi + A_lo*B_hi + A_hi*B_lo) for fp32-grade accuracy. Fragments are
// loaded straight from global (no LDS, no barriers). Epilogue fuses gates,
// h_new write (fp32 + bf16 hi/lo), and the fc_w partial-dot reduction.
//
// Verified layouts (guide m89/m91/m120):
//   A[m][k]: m = lane&15, k = (lane>>4)*8 + reg   (b128 from row-major h)
//   B[k][n]: n = lane&15, k = (lane>>4)*8 + reg   (b128 from swizzled W)
//   C/D:     col = lane&15, row = (lane>>4)*4 + reg
// ---------------------------------------------------------------------------
__global__ __launch_bounds__(64) void gru_step(
    const float* __restrict__ hf_in, const unsigned short* __restrict__ hhi_in,
    const unsigned short* __restrict__ hlo_in, float* __restrict__ hf_out,
    unsigned short* __restrict__ hhi_out, unsigned short* __restrict__ hlo_out,
    const unsigned short* __restrict__ whi, const unsigned short* __restrict__ wlo,
    const float* __restrict__ bias_ih, const float* __restrict__ bias_hh,
    const float* __restrict__ fc_w, float* __restrict__ delta_t) {
  const int lane = threadIdx.x;
  const int ln15 = lane & 15, quad = lane >> 4;
  const int m0 = blockIdx.x * 32;  // two 16-row tiles: m0, m0+16
  const int jt = blockIdx.y;
  const int j0 = jt * 16;

  floatx4 acc[2][3];
#pragma unroll
  for (int a = 0; a < 2; ++a)
#pragma unroll
    for (int g = 0; g < 3; ++g) acc[a][g] = (floatx4){0.f, 0.f, 0.f, 0.f};

  const unsigned short* a0h = hhi_in + (size_t)(m0 + ln15) * Hn + quad * 8;
  const unsigned short* a0l = hlo_in + (size_t)(m0 + ln15) * Hn + quad * 8;
  const unsigned short* a1h = a0h + 16 * Hn;
  const unsigned short* a1l = a0l + 16 * Hn;

  const unsigned short* bh[3];
  const unsigned short* bl[3];
#pragma unroll
  for (int g = 0; g < 3; ++g) {
    size_t base = ((size_t)(g * JTILES + jt) * KSTEPS) * 512 + (size_t)lane * 8;
    bh[g] = whi + base;
    bl[g] = wlo + base;
  }

  for (int ks = 0; ks < KSTEPS; ++ks) {
    short8 A0h = *(const short8*)(a0h + ks * 32);
    short8 A0l = *(const short8*)(a0l + ks * 32);
    short8 A1h = *(const short8*)(a1h + ks * 32);
    short8 A1l = *(const short8*)(a1l + ks * 32);
#pragma unroll
    for (int g = 0; g < 3; ++g) {
      short8 Bh = *(const short8*)(bh[g] + ks * 512);
      short8 Bl = *(const short8*)(bl[g] + ks * 512);
      acc[0][g] = __builtin_amdgcn_mfma_f32_16x16x32_bf16(A0h, Bh, acc[0][g], 0, 0, 0);
      acc[0][g] = __builtin_amdgcn_mfma_f32_16x16x32_bf16(A0l, Bh, acc[0][g], 0, 0, 0);
      acc[0][g] = __builtin_amdgcn_mfma_f32_16x16x32_bf16(A0h, Bl, acc[0][g], 0, 0, 0);
      acc[1][g] = __builtin_amdgcn_mfma_f32_16x16x32_bf16(A1h, Bh, acc[1][g], 0, 0, 0);
      acc[1][g] = __builtin_amdgcn_mfma_f32_16x16x32_bf16(A1l, Bh, acc[1][g], 0, 0, 0);
      acc[1][g] = __builtin_amdgcn_mfma_f32_16x16x32_bf16(A1h, Bl, acc[1][g], 0, 0, 0);
    }
  }

  // Epilogue: gates + h update + fc partial dot
  const int j = j0 + ln15;
  const float bir = bias_ih[j], biz = bias_ih[Hn + j], bin = bias_ih[2 * Hn + j];
  const float bhr = bias_hh[j], bhz = bias_hh[Hn + j], bhn = bias_hh[2 * Hn + j];
  const float fw = fc_w[j];
#pragma unroll
  for (int mt = 0; mt < 2; ++mt) {
    const int mb = m0 + mt * 16;
#pragma unroll
    for (int i = 0; i < 4; ++i) {
      const int b = mb + quad * 4 + i;
      float gr = bir + bhr + acc[mt][0][i];
      float gz = biz + bhz + acc[mt][1][i];
      float r = 1.f / (1.f + __expf(-gr));
      float z = 1.f / (1.f + __expf(-gz));
      float gn = bin + r * (acc[mt][2][i] + bhn);
      float nn = 1.f - 2.f / (1.f + __expf(2.f * gn));  // tanh(gn)
      float hold = hf_in[(size_t)b * Hn + j];
      float hn = (1.f - z) * nn + z * hold;
      hf_out[(size_t)b * Hn + j] = hn;
      unsigned short hb = f2bf(hn);
      hhi_out[(size_t)b * Hn + j] = hb;
      hlo_out[(size_t)b * Hn + j] = f2bf(hn - bf2f(hb));
      float p = hn * fw;  // reduce over the 16 j's held by this quad-row
      p += __shfl_xor(p, 1);
      p += __shfl_xor(p, 2);
      p += __shfl_xor(p, 4);
      p += __shfl_xor(p, 8);
      if (ln15 == 0) atomicAdd(&delta_t[b], p);
    }
  }
}

// ---------------------------------------------------------------------------
// Post: softplus -> inclusive scan over T -> normalize -> assemble output.
// One block per batch row, 128 threads.
// ---------------------------------------------------------------------------
__global__ void post_k(const float* __restrict__ ddot,
                       const float* __restrict__ fc_b,
                       const int* __restrict__ npred, float* __restrict__ out) {
  const int b = blockIdx.x;
  const int t = threadIdx.x;  // 0..127
  __shared__ float s[Tn];
  float x = ddot[(size_t)t * Bn + b] + fc_b[0];
  float sp = (x > 20.f) ? x : log1pf(__expf(x));
  s[t] = sp;
  __syncthreads();
  for (int off = 1; off < Tn; off <<= 1) {
    float v = s[t];
    float add = (t >= off) ? s[t - off] : 0.f;
    __syncthreads();
    s[t] = v + add;
    __syncthreads();
  }
  const int n = npred[b];                 // 1..128
  const float last = s[n - 1] + 1e-6f;
  float body = (t < n) ? (s[t] / last) : 0.f;
  float* ob = out + (size_t)b * (Tn + 2);
  ob[1 + t] = body;
  if (t == 0) { ob[0] = 0.f; ob[Tn + 1] = 0.f; }
  __syncthreads();
  if (t == 0) ob[n + 1] = 1.f;
}

// ---------------------------------------------------------------------------
extern "C" void kernel_launch(void* const* d_in, const int* in_sizes, int n_in,
                              void* d_out, int out_size, void* d_ws, size_t ws_size,
                              hipStream_t stream) {
  const float* context   = (const float*)d_in[0];
  // d_in[1] = weight_ih: UNUSED by the reference computation
  const float* weight_hh = (const float*)d_in[2];
  const float* bias_ih   = (const float*)d_in[3];
  const float* bias_hh   = (const float*)d_in[4];
  const float* fc_w      = (const float*)d_in[5];
  const float* fc_b      = (const float*)d_in[6];
  const int*   npred     = (const int*)d_in[7];
  float* out = (float*)d_out;

  char* ws = (char*)d_ws;
  size_t o = 0;
  float* hf[2];
  unsigned short *hhi[2], *hlo[2];
  hf[0] = (float*)(ws + o); o += (size_t)Bn * Hn * 4;
  hf[1] = (float*)(ws + o); o += (size_t)Bn * Hn * 4;
  hhi[0] = (unsigned short*)(ws + o); o += (size_t)Bn * Hn * 2;
  hlo[0] = (unsigned short*)(ws + o); o += (size_t)Bn * Hn * 2;
  hhi[1] = (unsigned short*)(ws + o); o += (size_t)Bn * Hn * 2;
  hlo[1] = (unsigned short*)(ws + o); o += (size_t)Bn * Hn * 2;
  unsigned short* whi = (unsigned short*)(ws + o); o += (size_t)3 * Hn * Hn * 2;
  unsigned short* wlo = (unsigned short*)(ws + o); o += (size_t)3 * Hn * Hn * 2;
  float* ddot = (float*)(ws + o); o += (size_t)Tn * Bn * 4;
  // total ~10.4 MB of d_ws

  swz_w<<<dim3((2304 * (Hn / 8) + 255) / 256), dim3(256), 0, stream>>>(weight_hh, whi, wlo);
  init_h<<<dim3((Bn * Hn + 255) / 256), dim3(256), 0, stream>>>(context, hf[0], hhi[0], hlo[0], ddot);

  int cur = 0;
  for (int t = 0; t < Tn; ++t) {
    gru_step<<<dim3(8, JTILES), dim3(64), 0, stream>>>(
        hf[cur], hhi[cur], hlo[cur], hf[1 - cur], hhi[1 - cur], hlo[1 - cur],
        whi, wlo, bias_ih, bias_hh, fc_w, ddot + (size_t)t * Bn);
    cur ^= 1;
  }
  post_k<<<dim3(Bn), dim3(Tn), 0, stream>>>(ddot, fc_b, npred, out);
}